// Round 21
// baseline (124.655 us; speedup 1.0000x reference)
//
#include <hip/hip_runtime.h>
#include <math.h>

typedef float  f32x4  __attribute__((ext_vector_type(4)));
typedef int    i32x4  __attribute__((ext_vector_type(4)));

#define H      4096
#define E      64
#define TOPK   8
#define TILE_T 16
#define CK     256     // k per staged chunk
#define MS     4       // 64-k MFMA steps per chunk
#define NCH    16      // chunks

// W -> 5 balanced i8 limbs of round(w*2^41), B-fragment order for 16x16x64
// (R11-proven): Wb[((m*4+eq)*5+j)*1024 + lane*16 + slot], lane=(kgrp<<4)|(e&15)
__global__ __launch_bounds__(256)
void prep_w(const float* __restrict__ Wg, signed char* __restrict__ Wb)
{
  int n = blockIdx.x * 256 + threadIdx.x;   // 16384 = e(64) x m(64) x kgrp(4)
  int kgrp = n & 3, m = (n >> 2) & 63, e = n >> 8;
  const float* wp = Wg + e * 4096 + m * 64 + kgrp * 16;
  signed char lb[5][16];
  #pragma unroll
  for (int s = 0; s < 16; ++s) {
    long long v = (long long)rint((double)wp[s] * 2199023255552.0); // 2^41
    #pragma unroll
    for (int j = 0; j < 4; ++j) {
      signed char b = (signed char)(v & 0xff);
      lb[j][s] = b;
      v = (v - b) >> 8;
    }
    lb[4][s] = (signed char)v;
  }
  int lanei = (kgrp << 4) | (e & 15);
  int eq = e >> 4;
  #pragma unroll
  for (int j = 0; j < 5; ++j) {
    i32x4 d;
    #pragma unroll
    for (int r = 0; r < 4; ++r)
      d[r] = (lb[j][4*r] & 0xFF) | ((lb[j][4*r+1] & 0xFF) << 8)
           | ((lb[j][4*r+2] & 0xFF) << 16) | ((lb[j][4*r+3] & 0xFF) << 24);
    *(i32x4*)(Wb + (((size_t)(m * 4 + eq) * 5 + j) << 10) + lanei * 16) = d;
  }
}

// comp[e] = C0 * sum_k round(w*2^41), full K (R11-proven).
__global__ __launch_bounds__(64)
void comp_w(const float* __restrict__ Wg, double* __restrict__ compT)
{
  int e = blockIdx.x;
  int lane = threadIdx.x;
  double s = 0.0;
  #pragma unroll 4
  for (int i = 0; i < 64; ++i)
    s += rint((double)Wg[e * 4096 + i * 64 + lane] * 2199023255552.0);
  #pragma unroll
  for (int off = 32; off >= 1; off >>= 1)
    s += __shfl_xor(s, off);
  if (lane == 0) compT[e] = 8421504.0 * s;
}

// R21 = R20 coalesced staging + INTRA-BLOCK OVERLAP (R15's fix done right):
// per phase, hoist ALL 20 B loads into regs FIRST, then issue next-chunk X
// loads (in flight through the whole consume), consume with zero VMEM ops
// (B in regs -> vmcnt(4) counted wait, X hidden under MFMA), then CONV+write
// the other LDS buffer (X already landed). Double-buffered As, one barrier
// per phase. R20's model: X-wait 2.6 + B 2.4 + MFMA 1.9 serialized = 110us;
// overlapped target ~max(2.6, 2.4) per phase. Numerics identical R8-R20.
__global__ __launch_bounds__(256)
void moe_gate_i8(const float* __restrict__ X, const signed char* __restrict__ Wb,
                 const double* __restrict__ compT, float* __restrict__ out,
                 int n_tokens)
{
  __shared__ char As[32768];     // 2 x 16KB [kgrp16][limb4][tok16]x16B swizzled
  double* Ls = (double*)As;      // aliased epilogue logits [16][64]

  const int tid  = threadIdx.x;
  const int lane = tid & 63;
  const int w    = tid >> 6;     // expert quad 0..3 (also stager of 4 rows)
  const int t0   = blockIdx.x * TILE_T;
  const int l15  = lane & 15;
  const int kg   = lane >> 4;

  // ---- probe (lane,reg)->(row,col) readout (R11-proven) ----
  i32x4 z = {0, 0, 0, 0};
  int lab = l15 * 0x01010101;
  i32x4 onev = {0x01010101, 0x01010101, 0x01010101, 0x01010101};
  i32x4 labv = {lab, lab, lab, lab};
  i32x4 pr = __builtin_amdgcn_mfma_i32_16x16x64_i8(labv, onev, z, 0, 0, 0);
  i32x4 pc = __builtin_amdgcn_mfma_i32_16x16x64_i8(onev, labv, z, 0, 0, 0);
  int qrow[4], qcol[4];
  #pragma unroll
  for (int r = 0; r < 4; ++r) { qrow[r] = pr[r] >> 6; qcol[r] = pc[r] >> 6; }

  i32x4 acc3 = z, acc4 = z, acc5 = z, acc6 = z, acc7 = z;

  // staging (R20-proven): wave w stages rows w*4..w*4+3, one coalesced
  // f32x4 per row; per-lane CONV; b32 scatter at 2 lanes/bank (free)
  const int kgrp = lane >> 2;                  // 0..15
  const int wrd  = lane & 3;
  const int swzs = ((lane >> 3) & 7) << 4;     // ((kgrp>>1)&7)<<4
  const float* xbase = X + (size_t)t0 * H + lane * 4;

  const signed char* bpp = Wb + w * 5120 + lane * 16;

  f32x4 xr[4];

  // conv xr -> swizzled limb-plane writes into buffer at byte offset boff_
  #define CONVWRITE(boff_)                                                    \
  {                                                                           \
    _Pragma("unroll")                                                         \
    for (int q = 0; q < 4; ++q) {                                             \
      const int r = w * 4 + q;                                                \
      unsigned u0 = ((unsigned)(int)(xr[q][0] * 268435456.0f)) ^ 0x00808080u; \
      unsigned u1 = ((unsigned)(int)(xr[q][1] * 268435456.0f)) ^ 0x00808080u; \
      unsigned u2 = ((unsigned)(int)(xr[q][2] * 268435456.0f)) ^ 0x00808080u; \
      unsigned u3 = ((unsigned)(int)(xr[q][3] * 268435456.0f)) ^ 0x00808080u; \
      unsigned p01, p23, W0, W1, W2, W3;                                      \
      p01 = __builtin_amdgcn_perm(u1, u0, 0x04000400u);                       \
      p23 = __builtin_amdgcn_perm(u3, u2, 0x04000400u);                       \
      W0  = __builtin_amdgcn_perm(p23, p01, 0x05040100u);                     \
      p01 = __builtin_amdgcn_perm(u1, u0, 0x05010501u);                       \
      p23 = __builtin_amdgcn_perm(u3, u2, 0x05010501u);                       \
      W1  = __builtin_amdgcn_perm(p23, p01, 0x05040100u);                     \
      p01 = __builtin_amdgcn_perm(u1, u0, 0x06020602u);                       \
      p23 = __builtin_amdgcn_perm(u3, u2, 0x06020602u);                       \
      W2  = __builtin_amdgcn_perm(p23, p01, 0x05040100u);                     \
      p01 = __builtin_amdgcn_perm(u1, u0, 0x07030703u);                       \
      p23 = __builtin_amdgcn_perm(u3, u2, 0x07030703u);                       \
      W3  = __builtin_amdgcn_perm(p23, p01, 0x05040100u);                     \
      char* base = As + (boff_) + (kgrp << 10) + (((r << 4) ^ swzs))          \
                 + (wrd << 2);                                                \
      *(unsigned*)(base + 0x000) = W0;                                        \
      *(unsigned*)(base + 0x100) = W1;                                        \
      *(unsigned*)(base + 0x200) = W2;                                        \
      *(unsigned*)(base + 0x300) = W3;                                        \
    }                                                                         \
  }

  // ---- prologue: chunk 0 -> buf 0 ----
  #pragma unroll
  for (int q = 0; q < 4; ++q)
    xr[q] = *(const f32x4*)(xbase + (size_t)(w * 4 + q) * H);
  CONVWRITE(0);
  __syncthreads();

  for (int c = 0; c < NCH; ++c) {
    // 1) hoist ALL B loads for this chunk (issued FIRST -> counted wait)
    i32x4 bf[4][5];
    #pragma unroll
    for (int m = 0; m < MS; ++m)
      #pragma unroll
      for (int j = 0; j < 5; ++j)
        bf[m][j] = *(const i32x4*)(bpp + (size_t)m * 20480 + (j << 10));
    bpp += (size_t)MS * 20480;
    __builtin_amdgcn_sched_barrier(0);

    // 2) issue next-chunk X loads (in flight through the consume)
    if (c < NCH - 1) {
      #pragma unroll
      for (int q = 0; q < 4; ++q)
        xr[q] = *(const f32x4*)(xbase + (size_t)(w * 4 + q) * H + (c + 1) * CK);
    }
    __builtin_amdgcn_sched_barrier(0);

    // 3) consume buf[c&1]: zero VMEM ops (B in regs; ds_read + MFMA only)
    {
      const char* base_ = As + ((c & 1) << 14);
      #pragma unroll
      for (int m = 0; m < MS; ++m) {
        const int kq   = 4 * m + kg;
        const int swzr = ((kq >> 1) & 7) << 4;
        const char* abase = base_ + (kq << 10) + (((l15 << 4) ^ swzr));
        i32x4 a0 = *(const i32x4*)(abase + 0x000);
        i32x4 a1 = *(const i32x4*)(abase + 0x100);
        i32x4 a2 = *(const i32x4*)(abase + 0x200);
        i32x4 a3 = *(const i32x4*)(abase + 0x300);
        i32x4 b0 = bf[m][0], b1 = bf[m][1], b2 = bf[m][2];
        i32x4 b3 = bf[m][3], b4 = bf[m][4];
        acc3 = __builtin_amdgcn_mfma_i32_16x16x64_i8(a0, b3, acc3, 0, 0, 0);
        acc4 = __builtin_amdgcn_mfma_i32_16x16x64_i8(a0, b4, acc4, 0, 0, 0);
        acc5 = __builtin_amdgcn_mfma_i32_16x16x64_i8(a1, b4, acc5, 0, 0, 0);
        acc6 = __builtin_amdgcn_mfma_i32_16x16x64_i8(a2, b4, acc6, 0, 0, 0);
        acc7 = __builtin_amdgcn_mfma_i32_16x16x64_i8(a3, b4, acc7, 0, 0, 0);
        acc3 = __builtin_amdgcn_mfma_i32_16x16x64_i8(a1, b2, acc3, 0, 0, 0);
        acc4 = __builtin_amdgcn_mfma_i32_16x16x64_i8(a1, b3, acc4, 0, 0, 0);
        acc5 = __builtin_amdgcn_mfma_i32_16x16x64_i8(a2, b3, acc5, 0, 0, 0);
        acc6 = __builtin_amdgcn_mfma_i32_16x16x64_i8(a3, b3, acc6, 0, 0, 0);
        acc3 = __builtin_amdgcn_mfma_i32_16x16x64_i8(a2, b1, acc3, 0, 0, 0);
        acc4 = __builtin_amdgcn_mfma_i32_16x16x64_i8(a2, b2, acc4, 0, 0, 0);
        acc5 = __builtin_amdgcn_mfma_i32_16x16x64_i8(a3, b2, acc5, 0, 0, 0);
        acc3 = __builtin_amdgcn_mfma_i32_16x16x64_i8(a3, b0, acc3, 0, 0, 0);
        acc4 = __builtin_amdgcn_mfma_i32_16x16x64_i8(a3, b1, acc4, 0, 0, 0);
      }
    }

    // 4) convert next chunk (X landed during consume) -> other buffer
    if (c < NCH - 1) CONVWRITE(((c + 1) & 1) << 14);
    __syncthreads();
  }
  #undef CONVWRITE

  // ---- f64 combine: wave owns its 16x16 logits (R11-proven) ----
  #pragma unroll
  for (int r = 0; r < 4; ++r) {
    int ex = w * 16 + qcol[r];
    double part = (16777216.0              * (double)acc3[r]
                 + 4294967296.0            * (double)acc4[r]
                 + 1099511627776.0         * (double)acc5[r]
                 + 281474976710656.0       * (double)acc6[r]
                 + 72057594037927936.0     * (double)acc7[r]
                 + compT[ex]) * 1.6940658945086007e-21;
    Ls[qrow[r] * E + ex] = part;
  }
  __syncthreads();

  // ---- softmax + top-8: selection on f64 logits, weights in f32 ----
  for (int tt2 = 0; tt2 < 4; tt2++) {
    int t = w * 4 + tt2;
    double val = Ls[t * E + lane];

    double mx = val;
    #pragma unroll
    for (int off = 32; off >= 1; off >>= 1)
      mx = fmax(mx, __shfl_xor(mx, off));

    float p = expf((float)(val - mx));
    float S = p;
    #pragma unroll
    for (int off = 32; off >= 1; off >>= 1)
      S += __shfl_xor(S, off);

    double cur = val;
    float myw = 0.f; int myidx = 0;
    float psum = 0.f;
    #pragma unroll
    for (int r = 0; r < TOPK; r++) {
      double v = cur; int ii = lane;
      #pragma unroll
      for (int off = 32; off >= 1; off >>= 1) {
        double ov = __shfl_xor(v, off);
        int    oi = __shfl_xor(ii, off);
        if (ov > v || (ov == v && oi < ii)) { v = ov; ii = oi; }
      }
      float pw = __shfl(p, ii);
      psum += pw;
      if (lane == r) { myw = pw; myidx = ii; }
      if (lane == ii) cur = -INFINITY;
    }
    float denom = psum + 1e-20f * S;
    if (lane < TOPK) {
      size_t gt = (size_t)(t0 + t);
      out[gt * TOPK + lane] = myw / denom;
      out[(size_t)n_tokens * TOPK + gt * TOPK + lane] = (float)myidx;
    }
  }
}

extern "C" void kernel_launch(void* const* d_in, const int* in_sizes, int n_in,
                              void* d_out, int out_size, void* d_ws, size_t ws_size,
                              hipStream_t stream)
{
  const float* X  = (const float*)d_in[0];
  const float* Wg = (const float*)d_in[1];
  float* out = (float*)d_out;
  signed char* Wb = (signed char*)d_ws;                 // 1.25 MB limb planes
  double* compT   = (double*)((char*)d_ws + 1310720);   // 512 B comp table
  int n_tokens = in_sizes[0] / H;                        // 16384

  prep_w<<<64, 256, 0, stream>>>(Wg, Wb);
  comp_w<<<64, 64, 0, stream>>>(Wg, compT);
  moe_gate_i8<<<n_tokens / TILE_T, 256, 0, stream>>>(X, Wb, compT, out, n_tokens);
}